// Round 15
// baseline (4415.358 us; speedup 1.0000x reference)
//
#include <hip/hip_runtime.h>
#include <hip/hip_bf16.h>
#include <math.h>

// ---------------- constants ----------------
#define EMBED 1536
#define HEADS 24
#define HD 64
#define FFN 6144
#define NTOK 257          // sequence length (spatial)
#define BT 64             // b*t
#define TT 8              // frames
#define BV 8              // videos
#define TOK (NTOK*BT)     // 16448 token rows
#define DA 384            // adapter hidden
#define NRD 964
#define CHF 4112          // FFN-path row chunk (4 chunks; H0 lives in W1, H1 in SCR)

typedef __bf16 bf16x8_t __attribute__((ext_vector_type(8)));
typedef float  f32x4    __attribute__((ext_vector_type(4)));

__device__ __forceinline__ float gelu_f(float x){
    return 0.5f * x * (1.0f + erff(x * 0.7071067811865476f));
}
__device__ __forceinline__ float bf2f(ushort u){
    union { uint i; float f; } c; c.i = ((uint)u) << 16; return c.f;
}
__device__ __forceinline__ ushort f2bf(float f){
    union { float f; uint i; } c; c.f = f;
    uint r = (c.i + 0x7fffu + ((c.i >> 16) & 1u)) >> 16;
    return (ushort)r;
}

// async global->LDS, 16B per lane; LDS dest = wave-uniform base + lane*16; global src per-lane
typedef __attribute__((address_space(1))) const void gas_void;
typedef __attribute__((address_space(3))) void las_void;
__device__ __forceinline__ void glds16(const ushort* g, ushort* l){
    __builtin_amdgcn_global_load_lds((gas_void*)(uintptr_t)g, (las_void*)(uintptr_t)l, 16, 0, 0);
}

// ---------------- weight transpose + bf16 convert + scale: w[K][N] -> wt[N][K] ----------------
__global__ __launch_bounds__(256) void transpose_w(const float* __restrict__ w, ushort* __restrict__ wt,
                                                   int K, int N, float scale){
    __shared__ float t[32][33];
    const int n0 = blockIdx.x * 32, k0 = blockIdx.y * 32;
    const int tx = threadIdx.x & 31, ty = threadIdx.x >> 5;   // 32 x 8
    #pragma unroll
    for (int i = 0; i < 4; ++i)
        t[ty + 8*i][tx] = w[(size_t)(k0 + ty + 8*i) * N + n0 + tx];
    __syncthreads();
    #pragma unroll
    for (int i = 0; i < 4; ++i)
        wt[(size_t)(n0 + ty + 8*i) * K + k0 + tx] = f2bf(t[tx][ty + 8*i] * scale);
}

// ---------------- combined QKV bias: [q_b*0.125 | 0 | v_b] ----------------
__global__ void build_qkv_bias(const float* __restrict__ qb, const float* __restrict__ vb,
                               float* __restrict__ o){
    int c = blockIdx.x * 256 + threadIdx.x;
    if (c < 1536) o[c] = qb[c] * 0.125f;
    else if (c < 3072) o[c] = 0.f;
    else if (c < 4608) o[c] = vb[c - 3072];
}

// ---------------- LayerNorm (templated input dtype), bf16 output ----------------
template<typename TI>
__global__ __launch_bounds__(256) void ln_kernel(const TI* __restrict__ in, ushort* __restrict__ out,
                                                 const float* __restrict__ w, const float* __restrict__ b, int D){
    __shared__ float shs[4], shss[4];
    const int row = blockIdx.x;
    const TI* xr = in + (size_t)row * D;
    float s = 0.f, ss = 0.f;
    for (int i = threadIdx.x * 8; i < D; i += 2048){
        float vv[8];
        if constexpr (sizeof(TI) == 4){
            float4 a = *(const float4*)&xr[i];
            float4 c = *(const float4*)&xr[i + 4];
            vv[0]=a.x; vv[1]=a.y; vv[2]=a.z; vv[3]=a.w;
            vv[4]=c.x; vv[5]=c.y; vv[6]=c.z; vv[7]=c.w;
        } else {
            int4 u = *(const int4*)&xr[i];
            const ushort* up = (const ushort*)&u;
            #pragma unroll
            for (int j = 0; j < 8; ++j) vv[j] = bf2f(up[j]);
        }
        #pragma unroll
        for (int j = 0; j < 8; ++j){ s += vv[j]; ss += vv[j]*vv[j]; }
    }
    #pragma unroll
    for (int off = 32; off >= 1; off >>= 1){ s += __shfl_down(s, off); ss += __shfl_down(ss, off); }
    const int wid = threadIdx.x >> 6;
    if ((threadIdx.x & 63) == 0){ shs[wid] = s; shss[wid] = ss; }
    __syncthreads();
    s  = shs[0] + shs[1] + shs[2] + shs[3];
    ss = shss[0] + shss[1] + shss[2] + shss[3];
    const float mu  = s / D;
    const float inv = rsqrtf(ss / D - mu * mu + 1e-5f);
    ushort* orow = out + (size_t)row * D;
    for (int i = threadIdx.x * 8; i < D; i += 2048){
        float vv[8];
        if constexpr (sizeof(TI) == 4){
            float4 a = *(const float4*)&xr[i];
            float4 c = *(const float4*)&xr[i + 4];
            vv[0]=a.x; vv[1]=a.y; vv[2]=a.z; vv[3]=a.w;
            vv[4]=c.x; vv[5]=c.y; vv[6]=c.z; vv[7]=c.w;
        } else {
            int4 u = *(const int4*)&xr[i];
            const ushort* up = (const ushort*)&u;
            #pragma unroll
            for (int j = 0; j < 8; ++j) vv[j] = bf2f(up[j]);
        }
        ushort ov[8];
        #pragma unroll
        for (int j = 0; j < 8; ++j)
            ov[j] = f2bf((vv[j] - mu) * inv * w[i + j] + b[i + j]);
        *(int4*)&orow[i] = *(const int4*)ov;
    }
}

// ---------------- fused gate (a*b) + LayerNorm, bf16 in/out ----------------
__global__ __launch_bounds__(256) void lnmul_kernel(const ushort* __restrict__ ina, const ushort* __restrict__ inb,
                                                    ushort* __restrict__ out,
                                                    const float* __restrict__ w, const float* __restrict__ b, int D){
    __shared__ float shs[4], shss[4];
    const int row = blockIdx.x;
    const ushort* ar = ina + (size_t)row * D;
    const ushort* br = inb + (size_t)row * D;
    float s = 0.f, ss = 0.f;
    for (int i = threadIdx.x * 8; i < D; i += 2048){
        int4 ua = *(const int4*)&ar[i];
        int4 ub = *(const int4*)&br[i];
        const ushort* pa = (const ushort*)&ua;
        const ushort* pb = (const ushort*)&ub;
        #pragma unroll
        for (int j = 0; j < 8; ++j){ float v = bf2f(pa[j]) * bf2f(pb[j]); s += v; ss += v*v; }
    }
    #pragma unroll
    for (int off = 32; off >= 1; off >>= 1){ s += __shfl_down(s, off); ss += __shfl_down(ss, off); }
    const int wid = threadIdx.x >> 6;
    if ((threadIdx.x & 63) == 0){ shs[wid] = s; shss[wid] = ss; }
    __syncthreads();
    s  = shs[0] + shs[1] + shs[2] + shs[3];
    ss = shss[0] + shss[1] + shss[2] + shss[3];
    const float mu  = s / D;
    const float inv = rsqrtf(ss / D - mu * mu + 1e-5f);
    ushort* orow = out + (size_t)row * D;
    for (int i = threadIdx.x * 8; i < D; i += 2048){
        int4 ua = *(const int4*)&ar[i];
        int4 ub = *(const int4*)&br[i];
        const ushort* pa = (const ushort*)&ua;
        const ushort* pb = (const ushort*)&ub;
        ushort ov[8];
        #pragma unroll
        for (int j = 0; j < 8; ++j){
            float v = bf2f(pa[j]) * bf2f(pb[j]);
            ov[j] = f2bf((v - mu) * inv * w[i + j] + b[i + j]);
        }
        *(int4*)&orow[i] = *(const int4*)ov;
    }
}

// ---------------- bf16 MFMA GEMM: dbuf global_load_lds, coalesced source, conflict-free read ----------------
// A[M][K] x Bt[N][K]^T -> C[M][N]
// Staging (per 16x32 subtile, one glds16 per wave): lane l sources row (l>>2) [4 consecutive
// lanes share one 64B row segment -> coalesced], k-chunk kb = (l&3)^(l>>4) [permuted within
// the row's 64B]. gload_lds writes lane l at slot l (linear, conflict-free).
// Fragment read: data (r,kb) lives at slot 4r + (kb^(r>>2)); per-16-lane phase the slots
// cover every 4-bank group exactly twice -> 2-way (free).
// Double-buffered: next tile's 4 glds issued before the MFMA phase; single __syncthreads
// per tile drains them after MFMA.  No XCD swizzle (linear block order keeps L2 locality).
// epilogue: v=acc; (+bias); gelu?; (+bf16 addb); (*gvec); (+bf16 addb2); (+f32 addf)
// mode 0: single C0. mode 1: QKV 3-way split (PERM layout). mode 2: FFN pair split.
__global__ __launch_bounds__(256) void mfma_gemm(
    const ushort* __restrict__ A, const ushort* __restrict__ Bt,
    int M, int N, int K,
    const float* __restrict__ bias, int dogelu,
    const ushort* __restrict__ addb, const float* __restrict__ gvec,
    const ushort* __restrict__ addb2, const float* __restrict__ addf,
    void* __restrict__ C0, void* __restrict__ C1, void* __restrict__ C2,
    int mode, int obf16)
{
    __shared__ ushort As[2][4096];   // dbuf x (8 subtiles x 64 slots x 8 ushorts)
    __shared__ ushort Bs[2][4096];
    const int tid  = threadIdx.x;
    const int lane = tid & 63, wv = tid >> 6;
    const int wr = wv >> 1, wc = wv & 1;
    const int row0 = blockIdx.y * 128, col0 = blockIdx.x * 128;

    // staging source for this lane: row-in-subtile l>>2, k-chunk (l&3)^(l>>4)
    const int srow = lane >> 2;
    const int skb  = (lane & 3) ^ (lane >> 4);
    // wave wv stages subtiles {2wv, 2wv+1}
    int rA0 = row0 + (2*wv)*16 + srow;     if (rA0 >= M) rA0 = M - 1;
    int rA1 = row0 + (2*wv+1)*16 + srow;   if (rA1 >= M) rA1 = M - 1;
    const ushort* Ap0 = A  + (size_t)rA0 * K + skb*8;
    const ushort* Ap1 = A  + (size_t)rA1 * K + skb*8;
    const ushort* Bp0 = Bt + (size_t)(col0 + (2*wv)*16 + srow) * K + skb*8;
    const ushort* Bp1 = Bt + (size_t)(col0 + (2*wv+1)*16 + srow) * K + skb*8;
    const int sb0 = (2*wv)   << 9;
    const int sb1 = (2*wv+1) << 9;
    // fragment-read slot for this lane: (r=lane&15, kb=lane>>4) -> 4r + (kb ^ (r>>2))
    const int rslot = (4*(lane & 15) + ((lane >> 4) ^ ((lane & 15) >> 2))) * 8;

    f32x4 acc[4][4] = {};
    const int nK = K >> 5;

    // prologue: stage tile 0 into buffer 0, full drain at barrier
    glds16(Ap0, &As[0][sb0]); glds16(Ap1, &As[0][sb1]);
    glds16(Bp0, &Bs[0][sb0]); glds16(Bp1, &Bs[0][sb1]);
    __syncthreads();

    int cur = 0;
    for (int ks = 0; ks < nK; ++ks){
        const int nxt = cur ^ 1;
        if (ks + 1 < nK){                    // issue next-tile loads; they fly under the MFMA phase
            const int ko = (ks + 1) << 5;
            glds16(Ap0 + ko, &As[nxt][sb0]); glds16(Ap1 + ko, &As[nxt][sb1]);
            glds16(Bp0 + ko, &Bs[nxt][sb0]); glds16(Bp1 + ko, &Bs[nxt][sb1]);
        }
        bf16x8_t af[4], bfr[4];
        #pragma unroll
        for (int mi = 0; mi < 4; ++mi)
            af[mi] = *(const bf16x8_t*)&As[cur][(((wr<<2)+mi) << 9) + rslot];
        #pragma unroll
        for (int ni = 0; ni < 4; ++ni)
            bfr[ni] = *(const bf16x8_t*)&Bs[cur][(((wc<<2)+ni) << 9) + rslot];
        #pragma unroll
        for (int mi = 0; mi < 4; ++mi)
            #pragma unroll
            for (int ni = 0; ni < 4; ++ni)
                acc[mi][ni] = __builtin_amdgcn_mfma_f32_16x16x32_bf16(af[mi], bfr[ni], acc[mi][ni], 0, 0, 0);
        __syncthreads();   // drains in-flight glds (they had the MFMA phase to fly) + read-done on cur
        cur = nxt;
    }

    // ---- output routing (block-uniform: 1536 and 6144 are multiples of 128) ----
    int cb = col0, Nout = N, gel = dogelu;
    void* Cp = C0;
    if (mode == 1){
        int seg = col0 / 1536;
        Cp = (seg == 0) ? C0 : ((seg == 1) ? C1 : C2);
        cb = col0 - seg * 1536; Nout = 1536;
    } else if (mode == 2){
        int seg = col0 / 6144;
        Cp = seg ? C1 : C0;
        cb = col0 - seg * 6144; Nout = 6144;
        if (seg) gel = 0;
    }

    const int fr = lane >> 4;   // 0..3
    const int fc = lane & 15;
    #pragma unroll
    for (int mi = 0; mi < 4; ++mi){
        #pragma unroll
        for (int j = 0; j < 4; ++j){
            const int rr = row0 + wr*64 + mi*16 + fr*4 + j;
            if (rr < M){
                #pragma unroll
                for (int ni = 0; ni < 4; ++ni){
                    const int cg = col0 + wc*64 + ni*16 + fc;          // global col (bias)
                    const int cl = cb   + wc*64 + ni*16 + fc;          // local col
                    float v = acc[mi][ni][j];
                    if (bias) v += bias[cg];
                    if (gel)  v = gelu_f(v);
                    if (addb)  v += bf2f(addb [(size_t)rr*Nout + cl]);
                    if (gvec)  v *= gvec[cl];
                    if (addb2) v += bf2f(addb2[(size_t)rr*Nout + cl]);
                    if (addf)  v += addf[(size_t)rr*Nout + cl];
                    if (mode == 1){
                        // perm layout: [bt][h][n][64]
                        const int nt = rr >> 6, btk = rr & 63;
                        const int hh = cl >> 6, dd = cl & 63;
                        ((ushort*)Cp)[(((size_t)btk*HEADS + hh)*NTOK + nt)*HD + dd] = f2bf(v);
                    } else if (obf16) {
                        ((ushort*)Cp)[(size_t)rr*Nout + cl] = f2bf(v);
                    } else {
                        ((float*) Cp)[(size_t)rr*Nout + cl] = v;
                    }
                }
            }
        }
    }
}

// ---------------- temporal attention v2: perm-layout inputs, row-major output ----------------
__global__ __launch_bounds__(64) void attn_temporal_v2(
    const ushort* __restrict__ Qp, const ushort* __restrict__ Kp, const ushort* __restrict__ Vp,
    ushort* __restrict__ Ot)
{
    const int h = blockIdx.x, n = blockIdx.y, b = blockIdx.z;
    const int d = threadIdx.x;
    __shared__ float qs[8][64], ks[8][64], vs[8][64];
    __shared__ float sc[8][8], pr[8][8];
    #pragma unroll
    for (int t = 0; t < 8; ++t){
        size_t r = (((size_t)(b*8 + t)*HEADS + h)*NTOK + n)*HD + d;
        qs[t][d] = bf2f(Qp[r]); ks[t][d] = bf2f(Kp[r]); vs[t][d] = bf2f(Vp[r]);
    }
    __syncthreads();
    {
        const int qi = d >> 3, kj = d & 7;
        float s = 0.f;
        #pragma unroll
        for (int e = 0; e < 64; ++e) s = fmaf(qs[qi][e], ks[kj][e], s);
        sc[qi][kj] = s;
    }
    __syncthreads();
    if (d < 8){
        float m = -3.4e38f;
        #pragma unroll
        for (int j = 0; j < 8; ++j) m = fmaxf(m, sc[d][j]);
        float sum = 0.f;
        #pragma unroll
        for (int j = 0; j < 8; ++j){ float e = expf(sc[d][j] - m); pr[d][j] = e; sum += e; }
        const float inv = 1.f / sum;
        #pragma unroll
        for (int j = 0; j < 8; ++j) pr[d][j] *= inv;
    }
    __syncthreads();
    #pragma unroll
    for (int qi = 0; qi < 8; ++qi){
        float o = 0.f;
        #pragma unroll
        for (int t = 0; t < 8; ++t) o = fmaf(pr[qi][t], vs[t][d], o);
        Ot[((size_t)n*64 + b*8 + qi) * EMBED + h*64 + d] = f2bf(o);
    }
}

// ---------------- spatial attention v3: MFMA flash, perm inputs, row-major output ----------------
__global__ __launch_bounds__(256) void attn_spatial_v3(
    const ushort* __restrict__ Qp, const ushort* __restrict__ Kp, const ushort* __restrict__ Vp,
    const ushort* __restrict__ bias, ushort* __restrict__ Ot)
{
    const int qt = blockIdx.x, bt = blockIdx.y, h = blockIdx.z;
    const int lane = threadIdx.x & 63, w = threadIdx.x >> 6;
    const int fr = lane >> 4, fc = lane & 15;
    const size_t base = ((size_t)bt*HEADS + h) * (NTOK*HD);
    __shared__ ushort Pb[64 * 328];
    __shared__ ushort Vt[64 * 72];

    const int q0 = qt * 64;

    int qr = q0 + w*16 + fc; if (qr > 256) qr = 256;
    bf16x8_t aq0 = *(const bf16x8_t*)(Qp + base + (size_t)qr*HD + fr*8);
    bf16x8_t aq1 = *(const bf16x8_t*)(Qp + base + (size_t)qr*HD + 32 + fr*8);

    f32x4 sacc[5][4];
    #pragma unroll
    for (int t = 0; t < 5; ++t){
        #pragma unroll
        for (int jn = 0; jn < 4; ++jn){
            int jr = t*64 + jn*16 + fc; if (jr > 256) jr = 256;
            bf16x8_t b0 = *(const bf16x8_t*)(Kp + base + (size_t)jr*HD + fr*8);
            bf16x8_t b1 = *(const bf16x8_t*)(Kp + base + (size_t)jr*HD + 32 + fr*8);
            f32x4 a = {};
            a = __builtin_amdgcn_mfma_f32_16x16x32_bf16(aq0, b0, a, 0, 0, 0);
            a = __builtin_amdgcn_mfma_f32_16x16x32_bf16(aq1, b1, a, 0, 0, 0);
            sacc[t][jn] = a;
        }
    }

    float m[4] = {-3.4e38f, -3.4e38f, -3.4e38f, -3.4e38f};
    #pragma unroll
    for (int jj = 0; jj < 4; ++jj){
        int n = q0 + w*16 + fr*4 + jj; if (n > 256) n = 256;
        const size_t brow = ((size_t)h*NTOK + n) * NTOK;
        #pragma unroll
        for (int t = 0; t < 5; ++t){
            #pragma unroll
            for (int jn = 0; jn < 4; ++jn){
                const int j = t*64 + jn*16 + fc;
                float s = sacc[t][jn][jj];
                if (j <= 256) s += bf2f(bias[brow + j]);
                else          s = -3.4e38f;
                sacc[t][jn][jj] = s;
                m[jj] = fmaxf(m[jj], s);
            }
        }
    }
    #pragma unroll
    for (int off = 1; off <= 8; off <<= 1){
        #pragma unroll
        for (int jj = 0; jj < 4; ++jj) m[jj] = fmaxf(m[jj], __shfl_xor(m[jj], off));
    }
    float sum[4] = {0.f, 0.f, 0.f, 0.f};
    #pragma unroll
    for (int t = 0; t < 5; ++t)
        #pragma unroll
        for (int jn = 0; jn < 4; ++jn)
            #pragma unroll
            for (int jj = 0; jj < 4; ++jj){
                float p = expf(sacc[t][jn][jj] - m[jj]);
                sacc[t][jn][jj] = p;
                sum[jj] += p;
            }
    #pragma unroll
    for (int off = 1; off <= 8; off <<= 1){
        #pragma unroll
        for (int jj = 0; jj < 4; ++jj) sum[jj] += __shfl_xor(sum[jj], off);
    }
    float inv[4];
    #pragma unroll
    for (int jj = 0; jj < 4; ++jj) inv[jj] = 1.f / sum[jj];

    #pragma unroll
    for (int t = 0; t < 5; ++t)
        #pragma unroll
        for (int jn = 0; jn < 4; ++jn)
            #pragma unroll
            for (int jj = 0; jj < 4; ++jj)
                Pb[(w*16 + fr*4 + jj) * 328 + t*64 + jn*16 + fc] = f2bf(sacc[t][jn][jj] * inv[jj]);

    f32x4 oacc[4] = {};
    for (int t = 0; t < 5; ++t){
        __syncthreads();
        {
            const int j = threadIdx.x >> 2, ds0 = (threadIdx.x & 3) * 16;
            int jr = t*64 + j; if (jr > 256) jr = 256;
            const ushort* src = Vp + base + (size_t)jr*HD + ds0;
            ushort tmp[16];
            *(int4*)tmp       = *(const int4*)src;
            *(int4*)(tmp + 8) = *(const int4*)(src + 8);
            #pragma unroll
            for (int i = 0; i < 16; ++i) Vt[(ds0 + i)*72 + j] = tmp[i];
        }
        __syncthreads();
        #pragma unroll
        for (int kj = 0; kj < 2; ++kj){
            bf16x8_t ap = *(const bf16x8_t*)&Pb[(w*16 + fc) * 328 + t*64 + kj*32 + fr*8];
            #pragma unroll
            for (int dn = 0; dn < 4; ++dn){
                bf16x8_t bv = *(const bf16x8_t*)&Vt[(dn*16 + fc) * 72 + kj*32 + fr*8];
                oacc[dn] = __builtin_amdgcn_mfma_f32_16x16x32_bf16(ap, bv, oacc[dn], 0, 0, 0);
            }
        }
    }

    #pragma unroll
    for (int jj = 0; jj < 4; ++jj){
        const int n = q0 + w*16 + fr*4 + jj;
        if (n <= 256){
            #pragma unroll
            for (int dn = 0; dn < 4; ++dn)
                Ot[((size_t)n*64 + bt) * EMBED + h*64 + dn*16 + fc] = f2bf(oacc[dn][jj]);
        }
    }
}

// ---------------- relative-position bias gather (bf16) ----------------
__global__ void bias_gather_kernel(const float* __restrict__ rpw, const int* __restrict__ bucket,
                                   ushort* __restrict__ bias){
    const int i = blockIdx.x * 256 + threadIdx.x;
    const int total = HEADS * NTOK * NTOK;
    if (i < total){
        const int h = i / (NTOK * NTOK);
        const int ij = i % (NTOK * NTOK);
        bias[i] = f2bf(rpw[(size_t)bucket[ij] * HEADS + h]);
    }
}

// ---------------- host-side helpers ----------------
static inline void g(const ushort* A, const ushort* Bt, int M, int N, int K,
                     const float* bias, int dogelu,
                     const ushort* addb, const float* gvec,
                     const ushort* addb2, const float* addf,
                     void* C0, void* C1, void* C2, int mode, int obf16, hipStream_t stream){
    dim3 grid(N / 128, (M + 127) / 128);
    mfma_gemm<<<grid, 256, 0, stream>>>(A, Bt, M, N, K, bias, dogelu, addb, gvec, addb2, addf,
                                        C0, C1, C2, mode, obf16);
}
static inline void tr(const float* w, ushort* wt, int K, int N, float sc, hipStream_t stream){
    transpose_w<<<dim3(N / 32, K / 32), 256, 0, stream>>>(w, wt, K, N, sc);
}

extern "C" void kernel_launch(void* const* d_in, const int* in_sizes, int n_in,
                              void* d_out, int out_size, void* d_ws, size_t ws_size,
                              hipStream_t stream){
    const float* x        = (const float*)d_in[0];
    const float* q_w      = (const float*)d_in[1];
    const float* k_w      = (const float*)d_in[2];
    const float* v_w      = (const float*)d_in[3];
    const float* out_w    = (const float*)d_in[4];
    const float* q_b      = (const float*)d_in[5];
    const float* v_b      = (const float*)d_in[6];
    const float* out_b    = (const float*)d_in[7];
    const float* attn_ln_w= (const float*)d_in[8];
    const float* attn_ln_b= (const float*)d_in[9];
    const float* sa_ln_w  = (const float*)d_in[10];
    const float* sa_ln_b  = (const float*)d_in[11];
    const float* fin_ln_w = (const float*)d_in[12];
    const float* fin_ln_b = (const float*)d_in[13];
    const float* wi0      = (const float*)d_in[14];
    const float* wi1      = (const float*)d_in[15];
    const float* ffn_ln_w = (const float*)d_in[16];
    const float* ffn_ln_b = (const float*)d_in[17];
    const float* ffn_out_w= (const float*)d_in[18];
    const float* ffn_out_b= (const float*)d_in[19];
    const float* gamma1   = (const float*)d_in[20];
    const float* gamma2   = (const float*)d_in[21];
    const float* t_fc1_w  = (const float*)d_in[22];
    const float* t_fc1_b  = (const float*)d_in[23];
    const float* t_fc2_w  = (const float*)d_in[24];
    const float* t_fc2_b  = (const float*)d_in[25];
    const float* s_fc1_w  = (const float*)d_in[26];
    const float* s_fc1_b  = (const float*)d_in[27];
    const float* s_fc2_w  = (const float*)d_in[28];
    const float* s_fc2_b  = (const float*)d_in[29];
    const float* m_fc1_w  = (const float*)d_in[30];
    const float* m_fc1_b  = (const float*)d_in[31];
    const float* m_fc2_w  = (const float*)d_in[32];
    const float* m_fc2_b  = (const float*)d_in[33];
    const float* rel_pos_w= (const float*)d_in[34];
    const int*   rp_bucket= (const int*)d_in[35];

    const size_t TOKD  = (size_t)TOK * EMBED;          // 25,264,128
    const size_t BIASZ = (size_t)HEADS * NTOK * NTOK;  //  1,585,176

    ushort* ws = (ushort*)d_ws;
    size_t off = 0;
    auto carve = [&](size_t n){ ushort* p = ws + off; off += n; return p; };

    // bf16-transposed weights
    ushort* WQKV = carve((size_t)4608 * EMBED);        // [Q|K|V] rows, Q pre-scaled by 0.125
    ushort* WTO  = carve((size_t)EMBED * EMBED);
    ushort* WI01 = carve((size_t)2 * FFN * EMBED);     // [wi0 | wi1] rows
    ushort* WTFO = carve((size_t)EMBED * FFN);
    ushort* WTT1 = carve((size_t)DA * EMBED);
    ushort* WTT2 = carve((size_t)EMBED * DA);
    ushort* WTS1 = carve((size_t)DA * EMBED);
    ushort* WTS2 = carve((size_t)EMBED * DA);
    ushort* WTM1 = carve((size_t)DA * EMBED);
    ushort* WTM2 = carve((size_t)EMBED * DA);
    // token-sized bf16 buffers (2 in ws; 2 more live in d_out)
    ushort* W0   = carve(TOKD);
    ushort* W1   = carve(TOKD);                        // FFN phase: hosts H0 (CHF x FFN <= TOKD)
    ushort* BIAS = carve(BIASZ);
    float*  B4608= (float*)carve(9216);                // 4608 fp32
    // SCR: adapter-hidden (attn phases) / H1 (ffn chunk loop)
    const size_t s_ab = (size_t)TOK * DA;              //  6,316,032
    const size_t s_h1 = (size_t)CHF * FFN;             // 25,264,128 (CHF=4112)
    ushort* SCR = carve(s_h1 > s_ab ? s_h1 : s_ab);
    ushort* AB  = SCR;                                 // TOK x DA (attention phases)
    ushort* H1  = SCR;                                 // CHF x FFN (ffn loop)
    ushort* H0  = W1;                                  // CHF x FFN (W1 dead through FFN section)

    const size_t need = off * sizeof(ushort);
    if (ws_size < need) return;   // diagnostic: zero output => ws too small

    // d_out hosts two bf16 token buffers; final fp32 result overwrites both
    ushort* DL = (ushort*)d_out;          // low half
    ushort* DH = (ushort*)d_out + TOKD;   // high half
    float*  out = (float*)d_out;

    // ---------------- weight prep ----------------
    tr(q_w,   WQKV,                      EMBED, EMBED, 0.125f, stream);
    tr(k_w,   WQKV + (size_t)1536*EMBED, EMBED, EMBED, 1.f, stream);
    tr(v_w,   WQKV + (size_t)3072*EMBED, EMBED, EMBED, 1.f, stream);
    tr(out_w, WTO,  EMBED, EMBED, 1.f, stream);
    tr(wi0,   WI01,                     EMBED, FFN, 1.f, stream);
    tr(wi1,   WI01 + (size_t)FFN*EMBED, EMBED, FFN, 1.f, stream);
    tr(ffn_out_w, WTFO, FFN, EMBED, 1.f, stream);
    tr(t_fc1_w, WTT1, EMBED, DA, 1.f, stream);
    tr(t_fc2_w, WTT2, DA, EMBED, 1.f, stream);
    tr(s_fc1_w, WTS1, EMBED, DA, 1.f, stream);
    tr(s_fc2_w, WTS2, DA, EMBED, 1.f, stream);
    tr(m_fc1_w, WTM1, EMBED, DA, 1.f, stream);
    tr(m_fc2_w, WTM2, DA, EMBED, 1.f, stream);
    build_qkv_bias<<<18, 256, 0, stream>>>(q_b, v_b, B4608);
    bias_gather_kernel<<<(HEADS*NTOK*NTOK + 255)/256, 256, 0, stream>>>(rel_pos_w, rp_bucket, BIAS);

    // ================= temporal attention =================
    ln_kernel<float><<<TOK, 256, 0, stream>>>(x, DH, sa_ln_w, sa_ln_b, EMBED);
    g(DH, WQKV, TOK, 4608, EMBED, B4608, 0, nullptr, nullptr, nullptr, nullptr,
      W0, W1, DL, 1, 1, stream);                                      // perm: Q->W0 K->W1 V->DL
    attn_temporal_v2<<<dim3(HEADS, NTOK, BV), 64, 0, stream>>>(W0, W1, DL, DH);  // At -> DH (row-major)
    ln_kernel<ushort><<<TOK, 256, 0, stream>>>(DH, W0, attn_ln_w, attn_ln_b, EMBED);
    g(W0, WTO, TOK, EMBED, EMBED, out_b, 0, nullptr, nullptr, nullptr, nullptr,
      W1, nullptr, nullptr, 0, 1, stream);                            // AO -> W1
    g(W1, WTT1, TOK, DA, EMBED, t_fc1_b, 1, nullptr, nullptr, nullptr, nullptr,
      AB, nullptr, nullptr, 0, 1, stream);
    g(AB, WTT2, TOK, EMBED, DA, t_fc2_b, 0, nullptr, nullptr, nullptr, x,
      DL, nullptr, nullptr, 0, 1, stream);                            // x1 = x + adapt_t -> DL

    // ================= spatial attention =================
    ln_kernel<ushort><<<TOK, 256, 0, stream>>>(DL, DH, sa_ln_w, sa_ln_b, EMBED);
    g(DH, WQKV, TOK, 4608, EMBED, B4608, 0, nullptr, nullptr, nullptr, nullptr,
      W0, W1, DL, 1, 1, stream);                                      // perm: Q->W0 K->W1 V->DL
    attn_spatial_v3<<<dim3(5, BT, HEADS), 256, 0, stream>>>(W0, W1, DL, BIAS, DH);  // O -> DH
    ln_kernel<ushort><<<TOK, 256, 0, stream>>>(DH, W0, attn_ln_w, attn_ln_b, EMBED);
    g(W0, WTO, TOK, EMBED, EMBED, out_b, 0, nullptr, nullptr, nullptr, nullptr,
      W1, nullptr, nullptr, 0, 1, stream);                            // aos -> W1
    g(W1, WTS1, TOK, DA, EMBED, s_fc1_b, 1, nullptr, nullptr, nullptr, nullptr,
      AB, nullptr, nullptr, 0, 1, stream);
    // x2 = x + gamma1*(aos + acc + s_fc2_b)  -> DL (bf16)
    g(AB, WTS2, TOK, EMBED, DA, s_fc2_b, 0, W1, gamma1, nullptr, x,
      DL, nullptr, nullptr, 0, 1, stream);

    // ================= FFN (GEGLU + inner LN) + adapter m + final combine =================
    // After this point W1 is dead -> reused as H0.
    ln_kernel<ushort><<<TOK, 256, 0, stream>>>(DL, DH, fin_ln_w, fin_ln_b, EMBED);   // xn -> DH
    g(DH, WTM1, TOK, DA, EMBED, m_fc1_b, 1, nullptr, nullptr, nullptr, nullptr,
      AB, nullptr, nullptr, 0, 1, stream);
    // Madd = x2 + adapter_m -> W0 (bf16)
    g(AB, WTM2, TOK, EMBED, DA, m_fc2_b, 0, DL, nullptr, nullptr, nullptr,
      W0, nullptr, nullptr, 0, 1, stream);
    for (int m0 = 0; m0 < TOK; m0 += CHF){
        const int mc = (TOK - m0 < CHF) ? (TOK - m0) : CHF;
        // H0 = gelu(xn@wi0), H1 = xn@wi1  (merged, N=12288)
        g(DH + (size_t)m0*EMBED, WI01, mc, 2*FFN, EMBED, nullptr, 2, nullptr, nullptr, nullptr, nullptr,
          H0, H1, nullptr, 2, 1, stream);
        lnmul_kernel<<<mc, 256, 0, stream>>>(H0, H1, H0, ffn_ln_w, ffn_ln_b, FFN);
        // out = gamma2*(acc + ffn_out_b) + Madd   (fp32 -> d_out)
        g(H0, WTFO, mc, EMBED, FFN, ffn_out_b, 0, nullptr, gamma2, W0 + (size_t)m0*EMBED, nullptr,
          out + (size_t)m0*EMBED, nullptr, nullptr, 0, 0, stream);
    }
}

// Round 16
// 4097.058 us; speedup vs baseline: 1.0777x; 1.0777x over previous
//
#include <hip/hip_runtime.h>
#include <hip/hip_bf16.h>
#include <math.h>

// ---------------- constants ----------------
#define EMBED 1536
#define HEADS 24
#define HD 64
#define FFN 6144
#define NTOK 257          // sequence length (spatial)
#define BT 64             // b*t
#define TT 8              // frames
#define BV 8              // videos
#define TOK (NTOK*BT)     // 16448 token rows
#define DA 384            // adapter hidden
#define NRD 964
#define CHF 4112          // FFN-path row chunk (4 chunks; H0 lives in W1, H1 in SCR)

typedef __bf16 bf16x8_t __attribute__((ext_vector_type(8)));
typedef float  f32x4    __attribute__((ext_vector_type(4)));

__device__ __forceinline__ float gelu_f(float x){
    return 0.5f * x * (1.0f + erff(x * 0.7071067811865476f));
}
__device__ __forceinline__ float bf2f(ushort u){
    union { uint i; float f; } c; c.i = ((uint)u) << 16; return c.f;
}
__device__ __forceinline__ ushort f2bf(float f){
    union { float f; uint i; } c; c.f = f;
    uint r = (c.i + 0x7fffu + ((c.i >> 16) & 1u)) >> 16;
    return (ushort)r;
}

// ---------------- weight transpose + bf16 convert + scale: w[K][N] -> wt[N][K] ----------------
__global__ __launch_bounds__(256) void transpose_w(const float* __restrict__ w, ushort* __restrict__ wt,
                                                   int K, int N, float scale){
    __shared__ float t[32][33];
    const int n0 = blockIdx.x * 32, k0 = blockIdx.y * 32;
    const int tx = threadIdx.x & 31, ty = threadIdx.x >> 5;   // 32 x 8
    #pragma unroll
    for (int i = 0; i < 4; ++i)
        t[ty + 8*i][tx] = w[(size_t)(k0 + ty + 8*i) * N + n0 + tx];
    __syncthreads();
    #pragma unroll
    for (int i = 0; i < 4; ++i)
        wt[(size_t)(n0 + ty + 8*i) * K + k0 + tx] = f2bf(t[tx][ty + 8*i] * scale);
}

// ---------------- combined QKV bias: [q_b*0.125 | 0 | v_b] ----------------
__global__ void build_qkv_bias(const float* __restrict__ qb, const float* __restrict__ vb,
                               float* __restrict__ o){
    int c = blockIdx.x * 256 + threadIdx.x;
    if (c < 1536) o[c] = qb[c] * 0.125f;
    else if (c < 3072) o[c] = 0.f;
    else if (c < 4608) o[c] = vb[c - 3072];
}

// ---------------- LayerNorm (templated input dtype), bf16 output ----------------
template<typename TI>
__global__ __launch_bounds__(256) void ln_kernel(const TI* __restrict__ in, ushort* __restrict__ out,
                                                 const float* __restrict__ w, const float* __restrict__ b, int D){
    __shared__ float shs[4], shss[4];
    const int row = blockIdx.x;
    const TI* xr = in + (size_t)row * D;
    float s = 0.f, ss = 0.f;
    for (int i = threadIdx.x * 8; i < D; i += 2048){
        float vv[8];
        if constexpr (sizeof(TI) == 4){
            float4 a = *(const float4*)&xr[i];
            float4 c = *(const float4*)&xr[i + 4];
            vv[0]=a.x; vv[1]=a.y; vv[2]=a.z; vv[3]=a.w;
            vv[4]=c.x; vv[5]=c.y; vv[6]=c.z; vv[7]=c.w;
        } else {
            int4 u = *(const int4*)&xr[i];
            const ushort* up = (const ushort*)&u;
            #pragma unroll
            for (int j = 0; j < 8; ++j) vv[j] = bf2f(up[j]);
        }
        #pragma unroll
        for (int j = 0; j < 8; ++j){ s += vv[j]; ss += vv[j]*vv[j]; }
    }
    #pragma unroll
    for (int off = 32; off >= 1; off >>= 1){ s += __shfl_down(s, off); ss += __shfl_down(ss, off); }
    const int wid = threadIdx.x >> 6;
    if ((threadIdx.x & 63) == 0){ shs[wid] = s; shss[wid] = ss; }
    __syncthreads();
    s  = shs[0] + shs[1] + shs[2] + shs[3];
    ss = shss[0] + shss[1] + shss[2] + shss[3];
    const float mu  = s / D;
    const float inv = rsqrtf(ss / D - mu * mu + 1e-5f);
    ushort* orow = out + (size_t)row * D;
    for (int i = threadIdx.x * 8; i < D; i += 2048){
        float vv[8];
        if constexpr (sizeof(TI) == 4){
            float4 a = *(const float4*)&xr[i];
            float4 c = *(const float4*)&xr[i + 4];
            vv[0]=a.x; vv[1]=a.y; vv[2]=a.z; vv[3]=a.w;
            vv[4]=c.x; vv[5]=c.y; vv[6]=c.z; vv[7]=c.w;
        } else {
            int4 u = *(const int4*)&xr[i];
            const ushort* up = (const ushort*)&u;
            #pragma unroll
            for (int j = 0; j < 8; ++j) vv[j] = bf2f(up[j]);
        }
        ushort ov[8];
        #pragma unroll
        for (int j = 0; j < 8; ++j)
            ov[j] = f2bf((vv[j] - mu) * inv * w[i + j] + b[i + j]);
        *(int4*)&orow[i] = *(const int4*)ov;
    }
}

// ---------------- fused gate (a*b) + LayerNorm, bf16 in/out ----------------
__global__ __launch_bounds__(256) void lnmul_kernel(const ushort* __restrict__ ina, const ushort* __restrict__ inb,
                                                    ushort* __restrict__ out,
                                                    const float* __restrict__ w, const float* __restrict__ b, int D){
    __shared__ float shs[4], shss[4];
    const int row = blockIdx.x;
    const ushort* ar = ina + (size_t)row * D;
    const ushort* br = inb + (size_t)row * D;
    float s = 0.f, ss = 0.f;
    for (int i = threadIdx.x * 8; i < D; i += 2048){
        int4 ua = *(const int4*)&ar[i];
        int4 ub = *(const int4*)&br[i];
        const ushort* pa = (const ushort*)&ua;
        const ushort* pb = (const ushort*)&ub;
        #pragma unroll
        for (int j = 0; j < 8; ++j){ float v = bf2f(pa[j]) * bf2f(pb[j]); s += v; ss += v*v; }
    }
    #pragma unroll
    for (int off = 32; off >= 1; off >>= 1){ s += __shfl_down(s, off); ss += __shfl_down(ss, off); }
    const int wid = threadIdx.x >> 6;
    if ((threadIdx.x & 63) == 0){ shs[wid] = s; shss[wid] = ss; }
    __syncthreads();
    s  = shs[0] + shs[1] + shs[2] + shs[3];
    ss = shss[0] + shss[1] + shss[2] + shss[3];
    const float mu  = s / D;
    const float inv = rsqrtf(ss / D - mu * mu + 1e-5f);
    ushort* orow = out + (size_t)row * D;
    for (int i = threadIdx.x * 8; i < D; i += 2048){
        int4 ua = *(const int4*)&ar[i];
        int4 ub = *(const int4*)&br[i];
        const ushort* pa = (const ushort*)&ua;
        const ushort* pb = (const ushort*)&ub;
        ushort ov[8];
        #pragma unroll
        for (int j = 0; j < 8; ++j){
            float v = bf2f(pa[j]) * bf2f(pb[j]);
            ov[j] = f2bf((v - mu) * inv * w[i + j] + b[i + j]);
        }
        *(int4*)&orow[i] = *(const int4*)ov;
    }
}

// ---------------- bf16 MFMA GEMM: r9 staging (coalesced global + XOR swizzle), BK=64 ----------------
// A[M][K] x Bt[N][K]^T -> C[M][N].  Requires K % 64 == 0.  (round-13/14 champion, byte-identical)
__global__ __launch_bounds__(256) void mfma_gemm(
    const ushort* __restrict__ A, const ushort* __restrict__ Bt,
    int M, int N, int K,
    const float* __restrict__ bias, int dogelu,
    const ushort* __restrict__ addb, const float* __restrict__ gvec,
    const ushort* __restrict__ addb2, const float* __restrict__ addf,
    void* __restrict__ C0, void* __restrict__ C1, void* __restrict__ C2,
    int mode, int obf16)
{
    __shared__ ushort As[8192];   // 2 k-groups x (8 subtiles x 64 slots x 8 ushorts)
    __shared__ ushort Bs[8192];
    const int tid  = threadIdx.x;
    const int lane = tid & 63, wv = tid >> 6;
    const int wr = wv >> 1, wc = wv & 1;
    const int row0 = blockIdx.y * 128, col0 = blockIdx.x * 128;

    const int crow = tid >> 2;          // 0..63
    const int ckb  = tid & 3;           // k-chunk of 8 within a 32-k group
    int ra0 = row0 + crow;       if (ra0 >= M) ra0 = M - 1;
    int ra1 = row0 + crow + 64;  if (ra1 >= M) ra1 = M - 1;
    const ushort* Ap0 = A  + (size_t)ra0 * K + ckb * 8;
    const ushort* Ap1 = A  + (size_t)ra1 * K + ckb * 8;
    const ushort* Bp0 = Bt + (size_t)(col0 + crow) * K + ckb * 8;
    const ushort* Bp1 = Bt + (size_t)(col0 + crow + 64) * K + ckb * 8;
    const int sslot = ((ckb << 4) | (crow & 15)) ^ (ckb << 2);
    const int d0 = ((crow >> 4) << 9) + sslot * 8;
    const int d1 = (((crow + 64) >> 4) << 9) + sslot * 8;
    const int lswz = (lane ^ ((lane >> 4) << 2)) * 8;

    f32x4 acc[4][4] = {};
    const int nK2 = K >> 6;

    int4 a0 = *(const int4*)Ap0,        a1 = *(const int4*)Ap1;
    int4 b0 = *(const int4*)Bp0,        b1 = *(const int4*)Bp1;
    int4 a2 = *(const int4*)(Ap0 + 32), a3 = *(const int4*)(Ap1 + 32);
    int4 b2 = *(const int4*)(Bp0 + 32), b3 = *(const int4*)(Bp1 + 32);

    for (int t = 0; t < nK2; ++t){
        __syncthreads();
        *(int4*)&As[d0] = a0;        *(int4*)&As[d1] = a1;
        *(int4*)&Bs[d0] = b0;        *(int4*)&Bs[d1] = b1;
        *(int4*)&As[4096 + d0] = a2; *(int4*)&As[4096 + d1] = a3;
        *(int4*)&Bs[4096 + d0] = b2; *(int4*)&Bs[4096 + d1] = b3;
        __syncthreads();
        if (t + 1 < nK2){
            const int ko = (t + 1) << 6;
            a0 = *(const int4*)(Ap0 + ko);      a1 = *(const int4*)(Ap1 + ko);
            b0 = *(const int4*)(Bp0 + ko);      b1 = *(const int4*)(Bp1 + ko);
            a2 = *(const int4*)(Ap0 + ko + 32); a3 = *(const int4*)(Ap1 + ko + 32);
            b2 = *(const int4*)(Bp0 + ko + 32); b3 = *(const int4*)(Bp1 + ko + 32);
        }
        #pragma unroll
        for (int h = 0; h < 2; ++h){
            const int hb = h << 12;
            bf16x8_t af[4], bfr[4];
            #pragma unroll
            for (int mi = 0; mi < 4; ++mi)
                af[mi] = *(const bf16x8_t*)&As[hb + (((wr<<2)+mi) << 9) + lswz];
            #pragma unroll
            for (int ni = 0; ni < 4; ++ni)
                bfr[ni] = *(const bf16x8_t*)&Bs[hb + (((wc<<2)+ni) << 9) + lswz];
            #pragma unroll
            for (int mi = 0; mi < 4; ++mi)
                #pragma unroll
                for (int ni = 0; ni < 4; ++ni)
                    acc[mi][ni] = __builtin_amdgcn_mfma_f32_16x16x32_bf16(af[mi], bfr[ni], acc[mi][ni], 0, 0, 0);
        }
    }

    int cb = col0, Nout = N, gel = dogelu;
    void* Cp = C0;
    if (mode == 1){
        int seg = col0 / 1536;
        Cp = (seg == 0) ? C0 : ((seg == 1) ? C1 : C2);
        cb = col0 - seg * 1536; Nout = 1536;
    } else if (mode == 2){
        int seg = col0 / 6144;
        Cp = seg ? C1 : C0;
        cb = col0 - seg * 6144; Nout = 6144;
        if (seg) gel = 0;
    }

    const int fr = lane >> 4;
    const int fc = lane & 15;
    #pragma unroll
    for (int mi = 0; mi < 4; ++mi){
        #pragma unroll
        for (int j = 0; j < 4; ++j){
            const int rr = row0 + wr*64 + mi*16 + fr*4 + j;
            if (rr < M){
                #pragma unroll
                for (int ni = 0; ni < 4; ++ni){
                    const int cg = col0 + wc*64 + ni*16 + fc;
                    const int cl = cb   + wc*64 + ni*16 + fc;
                    float v = acc[mi][ni][j];
                    if (bias) v += bias[cg];
                    if (gel)  v = gelu_f(v);
                    if (addb)  v += bf2f(addb [(size_t)rr*Nout + cl]);
                    if (gvec)  v *= gvec[cl];
                    if (addb2) v += bf2f(addb2[(size_t)rr*Nout + cl]);
                    if (addf)  v += addf[(size_t)rr*Nout + cl];
                    if (mode == 1){
                        const int nt = rr >> 6, btk = rr & 63;
                        const int hh = cl >> 6, dd = cl & 63;
                        ((ushort*)Cp)[(((size_t)btk*HEADS + hh)*NTOK + nt)*HD + dd] = f2bf(v);
                    } else if (obf16) {
                        ((ushort*)Cp)[(size_t)rr*Nout + cl] = f2bf(v);
                    } else {
                        ((float*) Cp)[(size_t)rr*Nout + cl] = v;
                    }
                }
            }
        }
    }
}

// ---------------- temporal attention v2: perm-layout inputs, row-major output ----------------
__global__ __launch_bounds__(64) void attn_temporal_v2(
    const ushort* __restrict__ Qp, const ushort* __restrict__ Kp, const ushort* __restrict__ Vp,
    ushort* __restrict__ Ot)
{
    const int h = blockIdx.x, n = blockIdx.y, b = blockIdx.z;
    const int d = threadIdx.x;
    __shared__ float qs[8][64], ks[8][64], vs[8][64];
    __shared__ float sc[8][8], pr[8][8];
    #pragma unroll
    for (int t = 0; t < 8; ++t){
        size_t r = (((size_t)(b*8 + t)*HEADS + h)*NTOK + n)*HD + d;
        qs[t][d] = bf2f(Qp[r]); ks[t][d] = bf2f(Kp[r]); vs[t][d] = bf2f(Vp[r]);
    }
    __syncthreads();
    {
        const int qi = d >> 3, kj = d & 7;
        float s = 0.f;
        #pragma unroll
        for (int e = 0; e < 64; ++e) s = fmaf(qs[qi][e], ks[kj][e], s);
        sc[qi][kj] = s;
    }
    __syncthreads();
    if (d < 8){
        float m = -3.4e38f;
        #pragma unroll
        for (int j = 0; j < 8; ++j) m = fmaxf(m, sc[d][j]);
        float sum = 0.f;
        #pragma unroll
        for (int j = 0; j < 8; ++j){ float e = expf(sc[d][j] - m); pr[d][j] = e; sum += e; }
        const float inv = 1.f / sum;
        #pragma unroll
        for (int j = 0; j < 8; ++j) pr[d][j] *= inv;
    }
    __syncthreads();
    #pragma unroll
    for (int qi = 0; qi < 8; ++qi){
        float o = 0.f;
        #pragma unroll
        for (int t = 0; t < 8; ++t) o = fmaf(pr[qi][t], vs[t][d], o);
        Ot[((size_t)n*64 + b*8 + qi) * EMBED + h*64 + d] = f2bf(o);
    }
}

// ---------------- spatial attention v3: MFMA flash, perm inputs, row-major output ----------------
__global__ __launch_bounds__(256) void attn_spatial_v3(
    const ushort* __restrict__ Qp, const ushort* __restrict__ Kp, const ushort* __restrict__ Vp,
    const ushort* __restrict__ bias, ushort* __restrict__ Ot)
{
    const int qt = blockIdx.x, bt = blockIdx.y, h = blockIdx.z;
    const int lane = threadIdx.x & 63, w = threadIdx.x >> 6;
    const int fr = lane >> 4, fc = lane & 15;
    const size_t base = ((size_t)bt*HEADS + h) * (NTOK*HD);
    __shared__ ushort Pb[64 * 328];
    __shared__ ushort Vt[64 * 72];

    const int q0 = qt * 64;

    int qr = q0 + w*16 + fc; if (qr > 256) qr = 256;
    bf16x8_t aq0 = *(const bf16x8_t*)(Qp + base + (size_t)qr*HD + fr*8);
    bf16x8_t aq1 = *(const bf16x8_t*)(Qp + base + (size_t)qr*HD + 32 + fr*8);

    f32x4 sacc[5][4];
    #pragma unroll
    for (int t = 0; t < 5; ++t){
        #pragma unroll
        for (int jn = 0; jn < 4; ++jn){
            int jr = t*64 + jn*16 + fc; if (jr > 256) jr = 256;
            bf16x8_t b0 = *(const bf16x8_t*)(Kp + base + (size_t)jr*HD + fr*8);
            bf16x8_t b1 = *(const bf16x8_t*)(Kp + base + (size_t)jr*HD + 32 + fr*8);
            f32x4 a = {};
            a = __builtin_amdgcn_mfma_f32_16x16x32_bf16(aq0, b0, a, 0, 0, 0);
            a = __builtin_amdgcn_mfma_f32_16x16x32_bf16(aq1, b1, a, 0, 0, 0);
            sacc[t][jn] = a;
        }
    }

    float m[4] = {-3.4e38f, -3.4e38f, -3.4e38f, -3.4e38f};
    #pragma unroll
    for (int jj = 0; jj < 4; ++jj){
        int n = q0 + w*16 + fr*4 + jj; if (n > 256) n = 256;
        const size_t brow = ((size_t)h*NTOK + n) * NTOK;
        #pragma unroll
        for (int t = 0; t < 5; ++t){
            #pragma unroll
            for (int jn = 0; jn < 4; ++jn){
                const int j = t*64 + jn*16 + fc;
                float s = sacc[t][jn][jj];
                if (j <= 256) s += bf2f(bias[brow + j]);
                else          s = -3.4e38f;
                sacc[t][jn][jj] = s;
                m[jj] = fmaxf(m[jj], s);
            }
        }
    }
    #pragma unroll
    for (int off = 1; off <= 8; off <<= 1){
        #pragma unroll
        for (int jj = 0; jj < 4; ++jj) m[jj] = fmaxf(m[jj], __shfl_xor(m[jj], off));
    }
    float sum[4] = {0.f, 0.f, 0.f, 0.f};
    #pragma unroll
    for (int t = 0; t < 5; ++t)
        #pragma unroll
        for (int jn = 0; jn < 4; ++jn)
            #pragma unroll
            for (int jj = 0; jj < 4; ++jj){
                float p = expf(sacc[t][jn][jj] - m[jj]);
                sacc[t][jn][jj] = p;
                sum[jj] += p;
            }
    #pragma unroll
    for (int off = 1; off <= 8; off <<= 1){
        #pragma unroll
        for (int jj = 0; jj < 4; ++jj) sum[jj] += __shfl_xor(sum[jj], off);
    }
    float inv[4];
    #pragma unroll
    for (int jj = 0; jj < 4; ++jj) inv[jj] = 1.f / sum[jj];

    #pragma unroll
    for (int t = 0; t < 5; ++t)
        #pragma unroll
        for (int jn = 0; jn < 4; ++jn)
            #pragma unroll
            for (int jj = 0; jj < 4; ++jj)
                Pb[(w*16 + fr*4 + jj) * 328 + t*64 + jn*16 + fc] = f2bf(sacc[t][jn][jj] * inv[jj]);

    f32x4 oacc[4] = {};
    for (int t = 0; t < 5; ++t){
        __syncthreads();
        {
            const int j = threadIdx.x >> 2, ds0 = (threadIdx.x & 3) * 16;
            int jr = t*64 + j; if (jr > 256) jr = 256;
            const ushort* src = Vp + base + (size_t)jr*HD + ds0;
            ushort tmp[16];
            *(int4*)tmp       = *(const int4*)src;
            *(int4*)(tmp + 8) = *(const int4*)(src + 8);
            #pragma unroll
            for (int i = 0; i < 16; ++i) Vt[(ds0 + i)*72 + j] = tmp[i];
        }
        __syncthreads();
        #pragma unroll
        for (int kj = 0; kj < 2; ++kj){
            bf16x8_t ap = *(const bf16x8_t*)&Pb[(w*16 + fc) * 328 + t*64 + kj*32 + fr*8];
            #pragma unroll
            for (int dn = 0; dn < 4; ++dn){
                bf16x8_t bv = *(const bf16x8_t*)&Vt[(dn*16 + fc) * 72 + kj*32 + fr*8];
                oacc[dn] = __builtin_amdgcn_mfma_f32_16x16x32_bf16(ap, bv, oacc[dn], 0, 0, 0);
            }
        }
    }

    #pragma unroll
    for (int jj = 0; jj < 4; ++jj){
        const int n = q0 + w*16 + fr*4 + jj;
        if (n <= 256){
            #pragma unroll
            for (int dn = 0; dn < 4; ++dn)
                Ot[((size_t)n*64 + bt) * EMBED + h*64 + dn*16 + fc] = f2bf(oacc[dn][jj]);
        }
    }
}

// ---------------- relative-position bias gather (bf16) ----------------
__global__ void bias_gather_kernel(const float* __restrict__ rpw, const int* __restrict__ bucket,
                                   ushort* __restrict__ bias){
    const int i = blockIdx.x * 256 + threadIdx.x;
    const int total = HEADS * NTOK * NTOK;
    if (i < total){
        const int h = i / (NTOK * NTOK);
        const int ij = i % (NTOK * NTOK);
        bias[i] = f2bf(rpw[(size_t)bucket[ij] * HEADS + h]);
    }
}

// ---------------- host-side helpers ----------------
static inline void g(const ushort* A, const ushort* Bt, int M, int N, int K,
                     const float* bias, int dogelu,
                     const ushort* addb, const float* gvec,
                     const ushort* addb2, const float* addf,
                     void* C0, void* C1, void* C2, int mode, int obf16, hipStream_t stream){
    dim3 grid(N / 128, (M + 127) / 128);
    mfma_gemm<<<grid, 256, 0, stream>>>(A, Bt, M, N, K, bias, dogelu, addb, gvec, addb2, addf,
                                        C0, C1, C2, mode, obf16);
}
static inline void tr(const float* w, ushort* wt, int K, int N, float sc, hipStream_t stream){
    transpose_w<<<dim3(N / 32, K / 32), 256, 0, stream>>>(w, wt, K, N, sc);
}

extern "C" void kernel_launch(void* const* d_in, const int* in_sizes, int n_in,
                              void* d_out, int out_size, void* d_ws, size_t ws_size,
                              hipStream_t stream){
    const float* x        = (const float*)d_in[0];
    const float* q_w      = (const float*)d_in[1];
    const float* k_w      = (const float*)d_in[2];
    const float* v_w      = (const float*)d_in[3];
    const float* out_w    = (const float*)d_in[4];
    const float* q_b      = (const float*)d_in[5];
    const float* v_b      = (const float*)d_in[6];
    const float* out_b    = (const float*)d_in[7];
    const float* attn_ln_w= (const float*)d_in[8];
    const float* attn_ln_b= (const float*)d_in[9];
    const float* sa_ln_w  = (const float*)d_in[10];
    const float* sa_ln_b  = (const float*)d_in[11];
    const float* fin_ln_w = (const float*)d_in[12];
    const float* fin_ln_b = (const float*)d_in[13];
    const float* wi0      = (const float*)d_in[14];
    const float* wi1      = (const float*)d_in[15];
    const float* ffn_ln_w = (const float*)d_in[16];
    const float* ffn_ln_b = (const float*)d_in[17];
    const float* ffn_out_w= (const float*)d_in[18];
    const float* ffn_out_b= (const float*)d_in[19];
    const float* gamma1   = (const float*)d_in[20];
    const float* gamma2   = (const float*)d_in[21];
    const float* t_fc1_w  = (const float*)d_in[22];
    const float* t_fc1_b  = (const float*)d_in[23];
    const float* t_fc2_w  = (const float*)d_in[24];
    const float* t_fc2_b  = (const float*)d_in[25];
    const float* s_fc1_w  = (const float*)d_in[26];
    const float* s_fc1_b  = (const float*)d_in[27];
    const float* s_fc2_w  = (const float*)d_in[28];
    const float* s_fc2_b  = (const float*)d_in[29];
    const float* m_fc1_w  = (const float*)d_in[30];
    const float* m_fc1_b  = (const float*)d_in[31];
    const float* m_fc2_w  = (const float*)d_in[32];
    const float* m_fc2_b  = (const float*)d_in[33];
    const float* rel_pos_w= (const float*)d_in[34];
    const int*   rp_bucket= (const int*)d_in[35];

    const size_t TOKD  = (size_t)TOK * EMBED;          // 25,264,128
    const size_t BIASZ = (size_t)HEADS * NTOK * NTOK;  //  1,585,176

    ushort* ws = (ushort*)d_ws;
    size_t off = 0;
    auto carve = [&](size_t n){ ushort* p = ws + off; off += n; return p; };

    // bf16-transposed weights
    ushort* WQKV = carve((size_t)4608 * EMBED);        // [Q|K|V] rows, Q pre-scaled by 0.125
    ushort* WTO  = carve((size_t)EMBED * EMBED);
    ushort* WI01 = carve((size_t)2 * FFN * EMBED);     // [wi0 | wi1] rows
    ushort* WTFO = carve((size_t)EMBED * FFN);
    ushort* WTT1 = carve((size_t)DA * EMBED);
    ushort* WTT2 = carve((size_t)EMBED * DA);
    ushort* WTS1 = carve((size_t)DA * EMBED);
    ushort* WTS2 = carve((size_t)EMBED * DA);
    ushort* WTM1 = carve((size_t)DA * EMBED);
    ushort* WTM2 = carve((size_t)EMBED * DA);
    // token-sized bf16 buffers (2 in ws; 2 more live in d_out)
    ushort* W0   = carve(TOKD);
    ushort* W1   = carve(TOKD);                        // FFN phase: hosts H0 (CHF x FFN == TOKD)
    ushort* BIAS = carve(BIASZ);
    float*  B4608= (float*)carve(9216);                // 4608 fp32
    // SCR: adapter-hidden (attn phases) / H1 (ffn chunk loop)
    const size_t s_ab = (size_t)TOK * DA;              //  6,316,032
    const size_t s_h1 = (size_t)CHF * FFN;             // 25,264,128 (CHF=4112)
    ushort* SCR = carve(s_h1 > s_ab ? s_h1 : s_ab);
    ushort* AB  = SCR;                                 // TOK x DA (attention phases)
    ushort* H1  = SCR;                                 // CHF x FFN (ffn loop)
    ushort* H0  = W1;                                  // CHF x FFN (W1 dead through FFN section)

    const size_t need = off * sizeof(ushort);
    if (ws_size < need) return;   // diagnostic: zero output => ws too small

    // d_out hosts two bf16 token buffers; final fp32 result overwrites both
    ushort* DL = (ushort*)d_out;          // low half
    ushort* DH = (ushort*)d_out + TOKD;   // high half
    float*  out = (float*)d_out;

    // ---------------- weight prep ----------------
    tr(q_w,   WQKV,                      EMBED, EMBED, 0.125f, stream);
    tr(k_w,   WQKV + (size_t)1536*EMBED, EMBED, EMBED, 1.f, stream);
    tr(v_w,   WQKV + (size_t)3072*EMBED, EMBED, EMBED, 1.f, stream);
    tr(out_w, WTO,  EMBED, EMBED, 1.f, stream);
    tr(wi0,   WI01,                     EMBED, FFN, 1.f, stream);
    tr(wi1,   WI01 + (size_t)FFN*EMBED, EMBED, FFN, 1.f, stream);
    tr(ffn_out_w, WTFO, FFN, EMBED, 1.f, stream);
    tr(t_fc1_w, WTT1, EMBED, DA, 1.f, stream);
    tr(t_fc2_w, WTT2, DA, EMBED, 1.f, stream);
    tr(s_fc1_w, WTS1, EMBED, DA, 1.f, stream);
    tr(s_fc2_w, WTS2, DA, EMBED, 1.f, stream);
    tr(m_fc1_w, WTM1, EMBED, DA, 1.f, stream);
    tr(m_fc2_w, WTM2, DA, EMBED, 1.f, stream);
    build_qkv_bias<<<18, 256, 0, stream>>>(q_b, v_b, B4608);
    bias_gather_kernel<<<(HEADS*NTOK*NTOK + 255)/256, 256, 0, stream>>>(rel_pos_w, rp_bucket, BIAS);

    // ================= temporal attention =================
    ln_kernel<float><<<TOK, 256, 0, stream>>>(x, DH, sa_ln_w, sa_ln_b, EMBED);
    g(DH, WQKV, TOK, 4608, EMBED, B4608, 0, nullptr, nullptr, nullptr, nullptr,
      W0, W1, DL, 1, 1, stream);                                      // perm: Q->W0 K->W1 V->DL
    attn_temporal_v2<<<dim3(HEADS, NTOK, BV), 64, 0, stream>>>(W0, W1, DL, DH);  // At -> DH (row-major)
    ln_kernel<ushort><<<TOK, 256, 0, stream>>>(DH, W0, attn_ln_w, attn_ln_b, EMBED);
    g(W0, WTO, TOK, EMBED, EMBED, out_b, 0, nullptr, nullptr, nullptr, nullptr,
      W1, nullptr, nullptr, 0, 1, stream);                            // AO -> W1
    g(W1, WTT1, TOK, DA, EMBED, t_fc1_b, 1, nullptr, nullptr, nullptr, nullptr,
      AB, nullptr, nullptr, 0, 1, stream);
    g(AB, WTT2, TOK, EMBED, DA, t_fc2_b, 0, nullptr, nullptr, nullptr, x,
      DL, nullptr, nullptr, 0, 1, stream);                            // x1 = x + adapt_t -> DL

    // ================= spatial attention =================
    ln_kernel<ushort><<<TOK, 256, 0, stream>>>(DL, DH, sa_ln_w, sa_ln_b, EMBED);
    g(DH, WQKV, TOK, 4608, EMBED, B4608, 0, nullptr, nullptr, nullptr, nullptr,
      W0, W1, DL, 1, 1, stream);                                      // perm: Q->W0 K->W1 V->DL
    attn_spatial_v3<<<dim3(5, BT, HEADS), 256, 0, stream>>>(W0, W1, DL, BIAS, DH);  // O -> DH
    ln_kernel<ushort><<<TOK, 256, 0, stream>>>(DH, W0, attn_ln_w, attn_ln_b, EMBED);
    g(W0, WTO, TOK, EMBED, EMBED, out_b, 0, nullptr, nullptr, nullptr, nullptr,
      W1, nullptr, nullptr, 0, 1, stream);                            // aos -> W1
    g(W1, WTS1, TOK, DA, EMBED, s_fc1_b, 1, nullptr, nullptr, nullptr, nullptr,
      AB, nullptr, nullptr, 0, 1, stream);
    // x2 = x + gamma1*(aos + acc + s_fc2_b)  -> DL (bf16)
    g(AB, WTS2, TOK, EMBED, DA, s_fc2_b, 0, W1, gamma1, nullptr, x,
      DL, nullptr, nullptr, 0, 1, stream);

    // ================= FFN (GEGLU + inner LN) + adapter m + final combine =================
    // After this point W1 is dead -> reused as H0.
    ln_kernel<ushort><<<TOK, 256, 0, stream>>>(DL, DH, fin_ln_w, fin_ln_b, EMBED);   // xn -> DH
    g(DH, WTM1, TOK, DA, EMBED, m_fc1_b, 1, nullptr, nullptr, nullptr, nullptr,
      AB, nullptr, nullptr, 0, 1, stream);
    // Madd = x2 + adapter_m -> W0 (bf16)
    g(AB, WTM2, TOK, EMBED, DA, m_fc2_b, 0, DL, nullptr, nullptr, nullptr,
      W0, nullptr, nullptr, 0, 1, stream);
    for (int m0 = 0; m0 < TOK; m0 += CHF){
        const int mc = (TOK - m0 < CHF) ? (TOK - m0) : CHF;
        // H0 = gelu(xn@wi0), H1 = xn@wi1  (merged, N=12288)
        g(DH + (size_t)m0*EMBED, WI01, mc, 2*FFN, EMBED, nullptr, 2, nullptr, nullptr, nullptr, nullptr,
          H0, H1, nullptr, 2, 1, stream);
        lnmul_kernel<<<mc, 256, 0, stream>>>(H0, H1, H0, ffn_ln_w, ffn_ln_b, FFN);
        // out = gamma2*(acc + ffn_out_b) + Madd   (fp32 -> d_out)
        g(H0, WTFO, mc, EMBED, FFN, ffn_out_b, 0, nullptr, gamma2, W0 + (size_t)m0*EMBED, nullptr,
          out + (size_t)m0*EMBED, nullptr, nullptr, 0, 0, stream);
    }
}

// Round 17
// 3585.093 us; speedup vs baseline: 1.2316x; 1.1428x over previous
//
#include <hip/hip_runtime.h>
#include <hip/hip_bf16.h>
#include <math.h>

// ---------------- constants ----------------
#define EMBED 1536
#define HEADS 24
#define HD 64
#define FFN 6144
#define NTOK 257          // sequence length (spatial)
#define BT 64             // b*t
#define TT 8              // frames
#define BV 8              // videos
#define TOK (NTOK*BT)     // 16448 token rows
#define DA 384            // adapter hidden
#define NRD 964
#define CHF 4112          // FFN-path row chunk (4 chunks; H0 lives in W1, H1 in SCR)

typedef __bf16 bf16x8_t __attribute__((ext_vector_type(8)));
typedef float  f32x4    __attribute__((ext_vector_type(4)));

__device__ __forceinline__ float gelu_f(float x){
    return 0.5f * x * (1.0f + erff(x * 0.7071067811865476f));
}
__device__ __forceinline__ float bf2f(ushort u){
    union { uint i; float f; } c; c.i = ((uint)u) << 16; return c.f;
}
__device__ __forceinline__ ushort f2bf(float f){
    union { float f; uint i; } c; c.f = f;
    uint r = (c.i + 0x7fffu + ((c.i >> 16) & 1u)) >> 16;
    return (ushort)r;
}

// ---------------- weight transpose + bf16 convert + scale: w[K][N] -> wt[N][K] ----------------
__global__ __launch_bounds__(256) void transpose_w(const float* __restrict__ w, ushort* __restrict__ wt,
                                                   int K, int N, float scale){
    __shared__ float t[32][33];
    const int n0 = blockIdx.x * 32, k0 = blockIdx.y * 32;
    const int tx = threadIdx.x & 31, ty = threadIdx.x >> 5;   // 32 x 8
    #pragma unroll
    for (int i = 0; i < 4; ++i)
        t[ty + 8*i][tx] = w[(size_t)(k0 + ty + 8*i) * N + n0 + tx];
    __syncthreads();
    #pragma unroll
    for (int i = 0; i < 4; ++i)
        wt[(size_t)(n0 + ty + 8*i) * K + k0 + tx] = f2bf(t[tx][ty + 8*i] * scale);
}

// ---------------- combined QKV bias: [q_b*0.125 | 0 | v_b] ----------------
__global__ void build_qkv_bias(const float* __restrict__ qb, const float* __restrict__ vb,
                               float* __restrict__ o){
    int c = blockIdx.x * 256 + threadIdx.x;
    if (c < 1536) o[c] = qb[c] * 0.125f;
    else if (c < 3072) o[c] = 0.f;
    else if (c < 4608) o[c] = vb[c - 3072];
}

// ---------------- LayerNorm (templated input dtype), bf16 output ----------------
template<typename TI>
__global__ __launch_bounds__(256) void ln_kernel(const TI* __restrict__ in, ushort* __restrict__ out,
                                                 const float* __restrict__ w, const float* __restrict__ b, int D){
    __shared__ float shs[4], shss[4];
    const int row = blockIdx.x;
    const TI* xr = in + (size_t)row * D;
    float s = 0.f, ss = 0.f;
    for (int i = threadIdx.x * 8; i < D; i += 2048){
        float vv[8];
        if constexpr (sizeof(TI) == 4){
            float4 a = *(const float4*)&xr[i];
            float4 c = *(const float4*)&xr[i + 4];
            vv[0]=a.x; vv[1]=a.y; vv[2]=a.z; vv[3]=a.w;
            vv[4]=c.x; vv[5]=c.y; vv[6]=c.z; vv[7]=c.w;
        } else {
            int4 u = *(const int4*)&xr[i];
            const ushort* up = (const ushort*)&u;
            #pragma unroll
            for (int j = 0; j < 8; ++j) vv[j] = bf2f(up[j]);
        }
        #pragma unroll
        for (int j = 0; j < 8; ++j){ s += vv[j]; ss += vv[j]*vv[j]; }
    }
    #pragma unroll
    for (int off = 32; off >= 1; off >>= 1){ s += __shfl_down(s, off); ss += __shfl_down(ss, off); }
    const int wid = threadIdx.x >> 6;
    if ((threadIdx.x & 63) == 0){ shs[wid] = s; shss[wid] = ss; }
    __syncthreads();
    s  = shs[0] + shs[1] + shs[2] + shs[3];
    ss = shss[0] + shss[1] + shss[2] + shss[3];
    const float mu  = s / D;
    const float inv = rsqrtf(ss / D - mu * mu + 1e-5f);
    ushort* orow = out + (size_t)row * D;
    for (int i = threadIdx.x * 8; i < D; i += 2048){
        float vv[8];
        if constexpr (sizeof(TI) == 4){
            float4 a = *(const float4*)&xr[i];
            float4 c = *(const float4*)&xr[i + 4];
            vv[0]=a.x; vv[1]=a.y; vv[2]=a.z; vv[3]=a.w;
            vv[4]=c.x; vv[5]=c.y; vv[6]=c.z; vv[7]=c.w;
        } else {
            int4 u = *(const int4*)&xr[i];
            const ushort* up = (const ushort*)&u;
            #pragma unroll
            for (int j = 0; j < 8; ++j) vv[j] = bf2f(up[j]);
        }
        ushort ov[8];
        #pragma unroll
        for (int j = 0; j < 8; ++j)
            ov[j] = f2bf((vv[j] - mu) * inv * w[i + j] + b[i + j]);
        *(int4*)&orow[i] = *(const int4*)ov;
    }
}

// ---------------- fused gate (a*b) + LayerNorm, bf16 in/out ----------------
__global__ __launch_bounds__(256) void lnmul_kernel(const ushort* __restrict__ ina, const ushort* __restrict__ inb,
                                                    ushort* __restrict__ out,
                                                    const float* __restrict__ w, const float* __restrict__ b, int D){
    __shared__ float shs[4], shss[4];
    const int row = blockIdx.x;
    const ushort* ar = ina + (size_t)row * D;
    const ushort* br = inb + (size_t)row * D;
    float s = 0.f, ss = 0.f;
    for (int i = threadIdx.x * 8; i < D; i += 2048){
        int4 ua = *(const int4*)&ar[i];
        int4 ub = *(const int4*)&br[i];
        const ushort* pa = (const ushort*)&ua;
        const ushort* pb = (const ushort*)&ub;
        #pragma unroll
        for (int j = 0; j < 8; ++j){ float v = bf2f(pa[j]) * bf2f(pb[j]); s += v; ss += v*v; }
    }
    #pragma unroll
    for (int off = 32; off >= 1; off >>= 1){ s += __shfl_down(s, off); ss += __shfl_down(ss, off); }
    const int wid = threadIdx.x >> 6;
    if ((threadIdx.x & 63) == 0){ shs[wid] = s; shss[wid] = ss; }
    __syncthreads();
    s  = shs[0] + shs[1] + shs[2] + shs[3];
    ss = shss[0] + shss[1] + shss[2] + shss[3];
    const float mu  = s / D;
    const float inv = rsqrtf(ss / D - mu * mu + 1e-5f);
    ushort* orow = out + (size_t)row * D;
    for (int i = threadIdx.x * 8; i < D; i += 2048){
        int4 ua = *(const int4*)&ar[i];
        int4 ub = *(const int4*)&br[i];
        const ushort* pa = (const ushort*)&ua;
        const ushort* pb = (const ushort*)&ub;
        ushort ov[8];
        #pragma unroll
        for (int j = 0; j < 8; ++j){
            float v = bf2f(pa[j]) * bf2f(pb[j]);
            ov[j] = f2bf((v - mu) * inv * w[i + j] + b[i + j]);
        }
        *(int4*)&orow[i] = *(const int4*)ov;
    }
}

// ---------------- bf16 MFMA GEMM: champion staging, 512 threads / 8 waves (occupancy lever) ----------------
// A[M][K] x Bt[N][K]^T -> C[M][N].  Requires K % 64 == 0.
// Same 128x128 tile, BK=64, coalesced global order + XOR-swizzled LDS as the r13/14 champion,
// but 8 waves x (64x32 per-wave tile): acc 32 regs, staging 16 regs -> ~90 regs/thread total,
// roughly doubling resident waves per CU vs the 256-thread variant's ~140 regs.
// Staging: thread t -> row crow=t>>2 (0..127; 4 consecutive lanes share a 64B row segment),
// k-chunk ckb=t&3; one A row + one B row per thread per 32-k group.
// epilogue: v=acc; (+bias); gelu?; (+bf16 addb); (*gvec); (+bf16 addb2); (+f32 addf)
// mode 0: single C0. mode 1: QKV 3-way split (PERM layout). mode 2: FFN pair split.
__global__ __launch_bounds__(512) void mfma_gemm(
    const ushort* __restrict__ A, const ushort* __restrict__ Bt,
    int M, int N, int K,
    const float* __restrict__ bias, int dogelu,
    const ushort* __restrict__ addb, const float* __restrict__ gvec,
    const ushort* __restrict__ addb2, const float* __restrict__ addf,
    void* __restrict__ C0, void* __restrict__ C1, void* __restrict__ C2,
    int mode, int obf16)
{
    __shared__ ushort As[8192];   // 2 k-groups x (8 subtiles x 64 slots x 8 ushorts)
    __shared__ ushort Bs[8192];
    const int tid  = threadIdx.x;
    const int lane = tid & 63, wv = tid >> 6;      // 8 waves
    const int wr = wv >> 2, wc = wv & 3;           // 2 x 4 -> per-wave 64 rows x 32 cols
    const int row0 = blockIdx.y * 128, col0 = blockIdx.x * 128;

    const int crow = tid >> 2;          // 0..127
    const int ckb  = tid & 3;           // k-chunk of 8 within a 32-k group
    int ra0 = row0 + crow;       if (ra0 >= M) ra0 = M - 1;
    const ushort* Ap0 = A  + (size_t)ra0 * K + ckb * 8;
    const ushort* Bp0 = Bt + (size_t)(col0 + crow) * K + ckb * 8;
    const int sslot = ((ckb << 4) | (crow & 15)) ^ (ckb << 2);
    const int d0 = ((crow >> 4) << 9) + sslot * 8;
    const int lswz = (lane ^ ((lane >> 4) << 2)) * 8;

    f32x4 acc[4][2] = {};
    const int nK2 = K >> 6;

    int4 a0 = *(const int4*)Ap0,        b0 = *(const int4*)Bp0;
    int4 a2 = *(const int4*)(Ap0 + 32), b2 = *(const int4*)(Bp0 + 32);

    for (int t = 0; t < nK2; ++t){
        __syncthreads();
        *(int4*)&As[d0] = a0;        *(int4*)&Bs[d0] = b0;
        *(int4*)&As[4096 + d0] = a2; *(int4*)&Bs[4096 + d0] = b2;
        __syncthreads();
        if (t + 1 < nK2){
            const int ko = (t + 1) << 6;
            a0 = *(const int4*)(Ap0 + ko);      b0 = *(const int4*)(Bp0 + ko);
            a2 = *(const int4*)(Ap0 + ko + 32); b2 = *(const int4*)(Bp0 + ko + 32);
        }
        #pragma unroll
        for (int h = 0; h < 2; ++h){
            const int hb = h << 12;
            bf16x8_t af[4], bfr[2];
            #pragma unroll
            for (int mi = 0; mi < 4; ++mi)
                af[mi] = *(const bf16x8_t*)&As[hb + (((wr*4 + mi)) << 9) + lswz];
            #pragma unroll
            for (int ni = 0; ni < 2; ++ni)
                bfr[ni] = *(const bf16x8_t*)&Bs[hb + (((wc*2 + ni)) << 9) + lswz];
            #pragma unroll
            for (int mi = 0; mi < 4; ++mi)
                #pragma unroll
                for (int ni = 0; ni < 2; ++ni)
                    acc[mi][ni] = __builtin_amdgcn_mfma_f32_16x16x32_bf16(af[mi], bfr[ni], acc[mi][ni], 0, 0, 0);
        }
    }

    int cb = col0, Nout = N, gel = dogelu;
    void* Cp = C0;
    if (mode == 1){
        int seg = col0 / 1536;
        Cp = (seg == 0) ? C0 : ((seg == 1) ? C1 : C2);
        cb = col0 - seg * 1536; Nout = 1536;
    } else if (mode == 2){
        int seg = col0 / 6144;
        Cp = seg ? C1 : C0;
        cb = col0 - seg * 6144; Nout = 6144;
        if (seg) gel = 0;
    }

    const int fr = lane >> 4;
    const int fc = lane & 15;
    #pragma unroll
    for (int mi = 0; mi < 4; ++mi){
        #pragma unroll
        for (int j = 0; j < 4; ++j){
            const int rr = row0 + wr*64 + mi*16 + fr*4 + j;
            if (rr < M){
                #pragma unroll
                for (int ni = 0; ni < 2; ++ni){
                    const int cg = col0 + wc*32 + ni*16 + fc;
                    const int cl = cb   + wc*32 + ni*16 + fc;
                    float v = acc[mi][ni][j];
                    if (bias) v += bias[cg];
                    if (gel)  v = gelu_f(v);
                    if (addb)  v += bf2f(addb [(size_t)rr*Nout + cl]);
                    if (gvec)  v *= gvec[cl];
                    if (addb2) v += bf2f(addb2[(size_t)rr*Nout + cl]);
                    if (addf)  v += addf[(size_t)rr*Nout + cl];
                    if (mode == 1){
                        const int nt = rr >> 6, btk = rr & 63;
                        const int hh = cl >> 6, dd = cl & 63;
                        ((ushort*)Cp)[(((size_t)btk*HEADS + hh)*NTOK + nt)*HD + dd] = f2bf(v);
                    } else if (obf16) {
                        ((ushort*)Cp)[(size_t)rr*Nout + cl] = f2bf(v);
                    } else {
                        ((float*) Cp)[(size_t)rr*Nout + cl] = v;
                    }
                }
            }
        }
    }
}

// ---------------- temporal attention v2: perm-layout inputs, row-major output ----------------
__global__ __launch_bounds__(64) void attn_temporal_v2(
    const ushort* __restrict__ Qp, const ushort* __restrict__ Kp, const ushort* __restrict__ Vp,
    ushort* __restrict__ Ot)
{
    const int h = blockIdx.x, n = blockIdx.y, b = blockIdx.z;
    const int d = threadIdx.x;
    __shared__ float qs[8][64], ks[8][64], vs[8][64];
    __shared__ float sc[8][8], pr[8][8];
    #pragma unroll
    for (int t = 0; t < 8; ++t){
        size_t r = (((size_t)(b*8 + t)*HEADS + h)*NTOK + n)*HD + d;
        qs[t][d] = bf2f(Qp[r]); ks[t][d] = bf2f(Kp[r]); vs[t][d] = bf2f(Vp[r]);
    }
    __syncthreads();
    {
        const int qi = d >> 3, kj = d & 7;
        float s = 0.f;
        #pragma unroll
        for (int e = 0; e < 64; ++e) s = fmaf(qs[qi][e], ks[kj][e], s);
        sc[qi][kj] = s;
    }
    __syncthreads();
    if (d < 8){
        float m = -3.4e38f;
        #pragma unroll
        for (int j = 0; j < 8; ++j) m = fmaxf(m, sc[d][j]);
        float sum = 0.f;
        #pragma unroll
        for (int j = 0; j < 8; ++j){ float e = expf(sc[d][j] - m); pr[d][j] = e; sum += e; }
        const float inv = 1.f / sum;
        #pragma unroll
        for (int j = 0; j < 8; ++j) pr[d][j] *= inv;
    }
    __syncthreads();
    #pragma unroll
    for (int qi = 0; qi < 8; ++qi){
        float o = 0.f;
        #pragma unroll
        for (int t = 0; t < 8; ++t) o = fmaf(pr[qi][t], vs[t][d], o);
        Ot[((size_t)n*64 + b*8 + qi) * EMBED + h*64 + d] = f2bf(o);
    }
}

// ---------------- spatial attention v3: MFMA flash, perm inputs, row-major output ----------------
__global__ __launch_bounds__(256) void attn_spatial_v3(
    const ushort* __restrict__ Qp, const ushort* __restrict__ Kp, const ushort* __restrict__ Vp,
    const ushort* __restrict__ bias, ushort* __restrict__ Ot)
{
    const int qt = blockIdx.x, bt = blockIdx.y, h = blockIdx.z;
    const int lane = threadIdx.x & 63, w = threadIdx.x >> 6;
    const int fr = lane >> 4, fc = lane & 15;
    const size_t base = ((size_t)bt*HEADS + h) * (NTOK*HD);
    __shared__ ushort Pb[64 * 328];
    __shared__ ushort Vt[64 * 72];

    const int q0 = qt * 64;

    int qr = q0 + w*16 + fc; if (qr > 256) qr = 256;
    bf16x8_t aq0 = *(const bf16x8_t*)(Qp + base + (size_t)qr*HD + fr*8);
    bf16x8_t aq1 = *(const bf16x8_t*)(Qp + base + (size_t)qr*HD + 32 + fr*8);

    f32x4 sacc[5][4];
    #pragma unroll
    for (int t = 0; t < 5; ++t){
        #pragma unroll
        for (int jn = 0; jn < 4; ++jn){
            int jr = t*64 + jn*16 + fc; if (jr > 256) jr = 256;
            bf16x8_t b0 = *(const bf16x8_t*)(Kp + base + (size_t)jr*HD + fr*8);
            bf16x8_t b1 = *(const bf16x8_t*)(Kp + base + (size_t)jr*HD + 32 + fr*8);
            f32x4 a = {};
            a = __builtin_amdgcn_mfma_f32_16x16x32_bf16(aq0, b0, a, 0, 0, 0);
            a = __builtin_amdgcn_mfma_f32_16x16x32_bf16(aq1, b1, a, 0, 0, 0);
            sacc[t][jn] = a;
        }
    }

    float m[4] = {-3.4e38f, -3.4e38f, -3.4e38f, -3.4e38f};
    #pragma unroll
    for (int jj = 0; jj < 4; ++jj){
        int n = q0 + w*16 + fr*4 + jj; if (n > 256) n = 256;
        const size_t brow = ((size_t)h*NTOK + n) * NTOK;
        #pragma unroll
        for (int t = 0; t < 5; ++t){
            #pragma unroll
            for (int jn = 0; jn < 4; ++jn){
                const int j = t*64 + jn*16 + fc;
                float s = sacc[t][jn][jj];
                if (j <= 256) s += bf2f(bias[brow + j]);
                else          s = -3.4e38f;
                sacc[t][jn][jj] = s;
                m[jj] = fmaxf(m[jj], s);
            }
        }
    }
    #pragma unroll
    for (int off = 1; off <= 8; off <<= 1){
        #pragma unroll
        for (int jj = 0; jj < 4; ++jj) m[jj] = fmaxf(m[jj], __shfl_xor(m[jj], off));
    }
    float sum[4] = {0.f, 0.f, 0.f, 0.f};
    #pragma unroll
    for (int t = 0; t < 5; ++t)
        #pragma unroll
        for (int jn = 0; jn < 4; ++jn)
            #pragma unroll
            for (int jj = 0; jj < 4; ++jj){
                float p = expf(sacc[t][jn][jj] - m[jj]);
                sacc[t][jn][jj] = p;
                sum[jj] += p;
            }
    #pragma unroll
    for (int off = 1; off <= 8; off <<= 1){
        #pragma unroll
        for (int jj = 0; jj < 4; ++jj) sum[jj] += __shfl_xor(sum[jj], off);
    }
    float inv[4];
    #pragma unroll
    for (int jj = 0; jj < 4; ++jj) inv[jj] = 1.f / sum[jj];

    #pragma unroll
    for (int t = 0; t < 5; ++t)
        #pragma unroll
        for (int jn = 0; jn < 4; ++jn)
            #pragma unroll
            for (int jj = 0; jj < 4; ++jj)
                Pb[(w*16 + fr*4 + jj) * 328 + t*64 + jn*16 + fc] = f2bf(sacc[t][jn][jj] * inv[jj]);

    f32x4 oacc[4] = {};
    for (int t = 0; t < 5; ++t){
        __syncthreads();
        {
            const int j = threadIdx.x >> 2, ds0 = (threadIdx.x & 3) * 16;
            int jr = t*64 + j; if (jr > 256) jr = 256;
            const ushort* src = Vp + base + (size_t)jr*HD + ds0;
            ushort tmp[16];
            *(int4*)tmp       = *(const int4*)src;
            *(int4*)(tmp + 8) = *(const int4*)(src + 8);
            #pragma unroll
            for (int i = 0; i < 16; ++i) Vt[(ds0 + i)*72 + j] = tmp[i];
        }
        __syncthreads();
        #pragma unroll
        for (int kj = 0; kj < 2; ++kj){
            bf16x8_t ap = *(const bf16x8_t*)&Pb[(w*16 + fc) * 328 + t*64 + kj*32 + fr*8];
            #pragma unroll
            for (int dn = 0; dn < 4; ++dn){
                bf16x8_t bv = *(const bf16x8_t*)&Vt[(dn*16 + fc) * 72 + kj*32 + fr*8];
                oacc[dn] = __builtin_amdgcn_mfma_f32_16x16x32_bf16(ap, bv, oacc[dn], 0, 0, 0);
            }
        }
    }

    #pragma unroll
    for (int jj = 0; jj < 4; ++jj){
        const int n = q0 + w*16 + fr*4 + jj;
        if (n <= 256){
            #pragma unroll
            for (int dn = 0; dn < 4; ++dn)
                Ot[((size_t)n*64 + bt) * EMBED + h*64 + dn*16 + fc] = f2bf(oacc[dn][jj]);
        }
    }
}

// ---------------- relative-position bias gather (bf16) ----------------
__global__ void bias_gather_kernel(const float* __restrict__ rpw, const int* __restrict__ bucket,
                                   ushort* __restrict__ bias){
    const int i = blockIdx.x * 256 + threadIdx.x;
    const int total = HEADS * NTOK * NTOK;
    if (i < total){
        const int h = i / (NTOK * NTOK);
        const int ij = i % (NTOK * NTOK);
        bias[i] = f2bf(rpw[(size_t)bucket[ij] * HEADS + h]);
    }
}

// ---------------- host-side helpers ----------------
static inline void g(const ushort* A, const ushort* Bt, int M, int N, int K,
                     const float* bias, int dogelu,
                     const ushort* addb, const float* gvec,
                     const ushort* addb2, const float* addf,
                     void* C0, void* C1, void* C2, int mode, int obf16, hipStream_t stream){
    dim3 grid(N / 128, (M + 127) / 128);
    mfma_gemm<<<grid, 512, 0, stream>>>(A, Bt, M, N, K, bias, dogelu, addb, gvec, addb2, addf,
                                        C0, C1, C2, mode, obf16);
}
static inline void tr(const float* w, ushort* wt, int K, int N, float sc, hipStream_t stream){
    transpose_w<<<dim3(N / 32, K / 32), 256, 0, stream>>>(w, wt, K, N, sc);
}

extern "C" void kernel_launch(void* const* d_in, const int* in_sizes, int n_in,
                              void* d_out, int out_size, void* d_ws, size_t ws_size,
                              hipStream_t stream){
    const float* x        = (const float*)d_in[0];
    const float* q_w      = (const float*)d_in[1];
    const float* k_w      = (const float*)d_in[2];
    const float* v_w      = (const float*)d_in[3];
    const float* out_w    = (const float*)d_in[4];
    const float* q_b      = (const float*)d_in[5];
    const float* v_b      = (const float*)d_in[6];
    const float* out_b    = (const float*)d_in[7];
    const float* attn_ln_w= (const float*)d_in[8];
    const float* attn_ln_b= (const float*)d_in[9];
    const float* sa_ln_w  = (const float*)d_in[10];
    const float* sa_ln_b  = (const float*)d_in[11];
    const float* fin_ln_w = (const float*)d_in[12];
    const float* fin_ln_b = (const float*)d_in[13];
    const float* wi0      = (const float*)d_in[14];
    const float* wi1      = (const float*)d_in[15];
    const float* ffn_ln_w = (const float*)d_in[16];
    const float* ffn_ln_b = (const float*)d_in[17];
    const float* ffn_out_w= (const float*)d_in[18];
    const float* ffn_out_b= (const float*)d_in[19];
    const float* gamma1   = (const float*)d_in[20];
    const float* gamma2   = (const float*)d_in[21];
    const float* t_fc1_w  = (const float*)d_in[22];
    const float* t_fc1_b  = (const float*)d_in[23];
    const float* t_fc2_w  = (const float*)d_in[24];
    const float* t_fc2_b  = (const float*)d_in[25];
    const float* s_fc1_w  = (const float*)d_in[26];
    const float* s_fc1_b  = (const float*)d_in[27];
    const float* s_fc2_w  = (const float*)d_in[28];
    const float* s_fc2_b  = (const float*)d_in[29];
    const float* m_fc1_w  = (const float*)d_in[30];
    const float* m_fc1_b  = (const float*)d_in[31];
    const float* m_fc2_w  = (const float*)d_in[32];
    const float* m_fc2_b  = (const float*)d_in[33];
    const float* rel_pos_w= (const float*)d_in[34];
    const int*   rp_bucket= (const int*)d_in[35];

    const size_t TOKD  = (size_t)TOK * EMBED;          // 25,264,128
    const size_t BIASZ = (size_t)HEADS * NTOK * NTOK;  //  1,585,176

    ushort* ws = (ushort*)d_ws;
    size_t off = 0;
    auto carve = [&](size_t n){ ushort* p = ws + off; off += n; return p; };

    // bf16-transposed weights
    ushort* WQKV = carve((size_t)4608 * EMBED);        // [Q|K|V] rows, Q pre-scaled by 0.125
    ushort* WTO  = carve((size_t)EMBED * EMBED);
    ushort* WI01 = carve((size_t)2 * FFN * EMBED);     // [wi0 | wi1] rows
    ushort* WTFO = carve((size_t)EMBED * FFN);
    ushort* WTT1 = carve((size_t)DA * EMBED);
    ushort* WTT2 = carve((size_t)EMBED * DA);
    ushort* WTS1 = carve((size_t)DA * EMBED);
    ushort* WTS2 = carve((size_t)EMBED * DA);
    ushort* WTM1 = carve((size_t)DA * EMBED);
    ushort* WTM2 = carve((size_t)EMBED * DA);
    // token-sized bf16 buffers (2 in ws; 2 more live in d_out)
    ushort* W0   = carve(TOKD);
    ushort* W1   = carve(TOKD);                        // FFN phase: hosts H0 (CHF x FFN == TOKD)
    ushort* BIAS = carve(BIASZ);
    float*  B4608= (float*)carve(9216);                // 4608 fp32
    // SCR: adapter-hidden (attn phases) / H1 (ffn chunk loop)
    const size_t s_ab = (size_t)TOK * DA;              //  6,316,032
    const size_t s_h1 = (size_t)CHF * FFN;             // 25,264,128 (CHF=4112)
    ushort* SCR = carve(s_h1 > s_ab ? s_h1 : s_ab);
    ushort* AB  = SCR;                                 // TOK x DA (attention phases)
    ushort* H1  = SCR;                                 // CHF x FFN (ffn loop)
    ushort* H0  = W1;                                  // CHF x FFN (W1 dead through FFN section)

    const size_t need = off * sizeof(ushort);
    if (ws_size < need) return;   // diagnostic: zero output => ws too small

    // d_out hosts two bf16 token buffers; final fp32 result overwrites both
    ushort* DL = (ushort*)d_out;          // low half
    ushort* DH = (ushort*)d_out + TOKD;   // high half
    float*  out = (float*)d_out;

    // ---------------- weight prep ----------------
    tr(q_w,   WQKV,                      EMBED, EMBED, 0.125f, stream);
    tr(k_w,   WQKV + (size_t)1536*EMBED, EMBED, EMBED, 1.f, stream);
    tr(v_w,   WQKV + (size_t)3072*EMBED, EMBED, EMBED, 1.f, stream);
    tr(out_w, WTO,  EMBED, EMBED, 1.f, stream);
    tr(wi0,   WI01,                     EMBED, FFN, 1.f, stream);
    tr(wi1,   WI01 + (size_t)FFN*EMBED, EMBED, FFN, 1.f, stream);
    tr(ffn_out_w, WTFO, FFN, EMBED, 1.f, stream);
    tr(t_fc1_w, WTT1, EMBED, DA, 1.f, stream);
    tr(t_fc2_w, WTT2, DA, EMBED, 1.f, stream);
    tr(s_fc1_w, WTS1, EMBED, DA, 1.f, stream);
    tr(s_fc2_w, WTS2, DA, EMBED, 1.f, stream);
    tr(m_fc1_w, WTM1, EMBED, DA, 1.f, stream);
    tr(m_fc2_w, WTM2, DA, EMBED, 1.f, stream);
    build_qkv_bias<<<18, 256, 0, stream>>>(q_b, v_b, B4608);
    bias_gather_kernel<<<(HEADS*NTOK*NTOK + 255)/256, 256, 0, stream>>>(rel_pos_w, rp_bucket, BIAS);

    // ================= temporal attention =================
    ln_kernel<float><<<TOK, 256, 0, stream>>>(x, DH, sa_ln_w, sa_ln_b, EMBED);
    g(DH, WQKV, TOK, 4608, EMBED, B4608, 0, nullptr, nullptr, nullptr, nullptr,
      W0, W1, DL, 1, 1, stream);                                      // perm: Q->W0 K->W1 V->DL
    attn_temporal_v2<<<dim3(HEADS, NTOK, BV), 64, 0, stream>>>(W0, W1, DL, DH);  // At -> DH (row-major)
    ln_kernel<ushort><<<TOK, 256, 0, stream>>>(DH, W0, attn_ln_w, attn_ln_b, EMBED);
    g(W0, WTO, TOK, EMBED, EMBED, out_b, 0, nullptr, nullptr, nullptr, nullptr,
      W1, nullptr, nullptr, 0, 1, stream);                            // AO -> W1
    g(W1, WTT1, TOK, DA, EMBED, t_fc1_b, 1, nullptr, nullptr, nullptr, nullptr,
      AB, nullptr, nullptr, 0, 1, stream);
    g(AB, WTT2, TOK, EMBED, DA, t_fc2_b, 0, nullptr, nullptr, nullptr, x,
      DL, nullptr, nullptr, 0, 1, stream);                            // x1 = x + adapt_t -> DL

    // ================= spatial attention =================
    ln_kernel<ushort><<<TOK, 256, 0, stream>>>(DL, DH, sa_ln_w, sa_ln_b, EMBED);
    g(DH, WQKV, TOK, 4608, EMBED, B4608, 0, nullptr, nullptr, nullptr, nullptr,
      W0, W1, DL, 1, 1, stream);                                      // perm: Q->W0 K->W1 V->DL
    attn_spatial_v3<<<dim3(5, BT, HEADS), 256, 0, stream>>>(W0, W1, DL, BIAS, DH);  // O -> DH
    ln_kernel<ushort><<<TOK, 256, 0, stream>>>(DH, W0, attn_ln_w, attn_ln_b, EMBED);
    g(W0, WTO, TOK, EMBED, EMBED, out_b, 0, nullptr, nullptr, nullptr, nullptr,
      W1, nullptr, nullptr, 0, 1, stream);                            // aos -> W1
    g(W1, WTS1, TOK, DA, EMBED, s_fc1_b, 1, nullptr, nullptr, nullptr, nullptr,
      AB, nullptr, nullptr, 0, 1, stream);
    // x2 = x + gamma1*(aos + acc + s_fc2_b)  -> DL (bf16)
    g(AB, WTS2, TOK, EMBED, DA, s_fc2_b, 0, W1, gamma1, nullptr, x,
      DL, nullptr, nullptr, 0, 1, stream);

    // ================= FFN (GEGLU + inner LN) + adapter m + final combine =================
    // After this point W1 is dead -> reused as H0.
    ln_kernel<ushort><<<TOK, 256, 0, stream>>>(DL, DH, fin_ln_w, fin_ln_b, EMBED);   // xn -> DH
    g(DH, WTM1, TOK, DA, EMBED, m_fc1_b, 1, nullptr, nullptr, nullptr, nullptr,
      AB, nullptr, nullptr, 0, 1, stream);
    // Madd = x2 + adapter_m -> W0 (bf16)
    g(AB, WTM2, TOK, EMBED, DA, m_fc2_b, 0, DL, nullptr, nullptr, nullptr,
      W0, nullptr, nullptr, 0, 1, stream);
    for (int m0 = 0; m0 < TOK; m0 += CHF){
        const int mc = (TOK - m0 < CHF) ? (TOK - m0) : CHF;
        // H0 = gelu(xn@wi0), H1 = xn@wi1  (merged, N=12288)
        g(DH + (size_t)m0*EMBED, WI01, mc, 2*FFN, EMBED, nullptr, 2, nullptr, nullptr, nullptr, nullptr,
          H0, H1, nullptr, 2, 1, stream);
        lnmul_kernel<<<mc, 256, 0, stream>>>(H0, H1, H0, ffn_ln_w, ffn_ln_b, FFN);
        // out = gamma2*(acc + ffn_out_b) + Madd   (fp32 -> d_out)
        g(H0, WTFO, mc, EMBED, FFN, ffn_out_b, 0, nullptr, gamma2, W0 + (size_t)m0*EMBED, nullptr,
          out + (size_t)m0*EMBED, nullptr, nullptr, 0, 0, stream);
    }
}